// Round 2
// baseline (409.356 us; speedup 1.0000x reference)
//
#include <hip/hip_runtime.h>

#define B_ 32
#define C_ 128
#define H_ 32
#define W_ 32
#define WN 63
// LDS: 2 h-buffers (17 rows x 128ch bf16) + x slice (512 rows x 128ch bf16)
#define HT_BYTES (2 * 17 * 256)
#define LDS_BYTES (HT_BYTES + 16 * 32 * 256)

typedef __attribute__((ext_vector_type(8))) short bf16x8;
typedef __attribute__((ext_vector_type(4))) float f32x4;
typedef __attribute__((ext_vector_type(4))) unsigned short us4;

__device__ __forceinline__ unsigned short f2bf(float f) {
  union { float f; unsigned u; } v; v.f = f;
  unsigned r = v.u + 0x7FFFu + ((v.u >> 16) & 1u);
  return (unsigned short)(r >> 16);
}

// ---------------------------------------------------------------------------
// Fused diagonal-LSTM scan. 64 blocks = (batch, half). Block (b,h) owns rows
// j in [16h, 16h+16). Pipeline: block (b,0) publishes its row-15 h each step
// (ghost row, 256B) + release flag; block (b,1) acquires it (lags ~const).
// Input GEMM fused: x slice staged once in LDS, W_is fragments in registers.
// One barrier per step via double-buffered hT.
// ---------------------------------------------------------------------------
__global__ __launch_bounds__(512, 2)
void scan_kernel(const float* __restrict__ x, const float* __restrict__ W_is,
                 const float* __restrict__ b_is, const float* __restrict__ Wss,
                 const float* __restrict__ b_ss, float* __restrict__ out,
                 int* __restrict__ flags, unsigned short* __restrict__ ghost) {
  extern __shared__ __align__(16) char lds[];
  unsigned short* hTd = (unsigned short*)lds;  // [2][17][128] bf16, swizzled
  char* xlsB = lds + HT_BYTES;                 // [16*32 rows][128 ch] bf16, swizzled

  const int bid = blockIdx.x;
  const int b = bid >> 1, half = bid & 1;
  const int j0 = half << 4;
  const int tid = threadIdx.x;
  const int w = tid >> 6, l = tid & 63;
  const int lg = l >> 4, lm = l & 15;
  const int chW = 16 * w;

  // ---- zero both h buffers (row 16 = permanent zero row) ----
  for (int i = tid; i < 2 * 17 * 128; i += 512) hTd[i] = 0;

  // ---- stage x slice -> LDS bf16 (one-time). row=(jl*32+c), swizzle by row&15.
  for (int it = 0; it < 128; ++it) {
    int idx = it * 512 + tid;
    int c = idx & 31, jl = (idx >> 5) & 15, ch = idx >> 9;
    float v = x[((b * C_ + ch) * H_ + j0 + jl) * W_ + c];
    int row = jl * 32 + c;
    int byteCol = ch * 2;
    int addr = row * 256 + ((((byteCol >> 4) ^ (row & 15))) << 4) + (byteCol & 15);
    *(unsigned short*)(xlsB + addr) = f2bf(v);
  }

  // ---- recurrent weights [W0|W1] in registers: Ass[g][kf], kf<4 -> W0 (h_up)
  bf16x8 Ass[4][8];
#pragma unroll
  for (int g = 0; g < 4; ++g) {
    const int o = g * 128 + chW + lm;
#pragma unroll
    for (int kf = 0; kf < 4; ++kf) {
      const int ch = kf * 32 + lg * 8;
      const float* wp = Wss + (o * C_ + ch) * 2;  // interleaved (W0,W1)
      f32x4 q0 = *(const f32x4*)(wp + 0);
      f32x4 q1 = *(const f32x4*)(wp + 4);
      f32x4 q2 = *(const f32x4*)(wp + 8);
      f32x4 q3 = *(const f32x4*)(wp + 12);
      bf16x8 a0, a1;
      a0[0] = (short)f2bf(q0[0]); a1[0] = (short)f2bf(q0[1]);
      a0[1] = (short)f2bf(q0[2]); a1[1] = (short)f2bf(q0[3]);
      a0[2] = (short)f2bf(q1[0]); a1[2] = (short)f2bf(q1[1]);
      a0[3] = (short)f2bf(q1[2]); a1[3] = (short)f2bf(q1[3]);
      a0[4] = (short)f2bf(q2[0]); a1[4] = (short)f2bf(q2[1]);
      a0[5] = (short)f2bf(q2[2]); a1[5] = (short)f2bf(q2[3]);
      a0[6] = (short)f2bf(q3[0]); a1[6] = (short)f2bf(q3[1]);
      a0[7] = (short)f2bf(q3[2]); a1[7] = (short)f2bf(q3[3]);
      Ass[g][kf] = a0;
      Ass[g][kf + 4] = a1;
    }
  }
  // ---- input weights W_is in registers: Ais[g][kf]
  bf16x8 Ais[4][4];
#pragma unroll
  for (int g = 0; g < 4; ++g) {
    const int o = g * 128 + chW + lm;
#pragma unroll
    for (int kf = 0; kf < 4; ++kf) {
      const float* wp = W_is + o * C_ + kf * 32 + lg * 8;
      f32x4 wa = *(const f32x4*)(wp);
      f32x4 wb = *(const f32x4*)(wp + 4);
      bf16x8 af;
      af[0] = (short)f2bf(wa[0]); af[1] = (short)f2bf(wa[1]);
      af[2] = (short)f2bf(wa[2]); af[3] = (short)f2bf(wa[3]);
      af[4] = (short)f2bf(wb[0]); af[5] = (short)f2bf(wb[1]);
      af[6] = (short)f2bf(wb[2]); af[7] = (short)f2bf(wb[3]);
      Ais[g][kf] = af;
    }
  }

  float bs[4][4];
#pragma unroll
  for (int g = 0; g < 4; ++g)
#pragma unroll
    for (int r = 0; r < 4; ++r) {
      int o = g * 128 + chW + lg * 4 + r;
      bs[g][r] = b_is[o] + b_ss[o];
    }

  float cst[4] = {0.f, 0.f, 0.f, 0.f};
  const int TSTOP = half ? WN : 47;  // rows 0..15 all dead for t>=47
  int* flag_b = flags + b;
  unsigned short* ghost_b = ghost + (b << 6) * 128;  // [64 t-slots][128 ch]

  // h writeback address (within one buffer)
  int wAddr;
  {
    int byteCol = chW * 2 + lg * 8;
    wAddr = lm * 256 + (((byteCol >> 4) ^ (lm & 15)) << 4) + (byteCol & 15);
  }

  __syncthreads();

  for (int t = 0; t < TSTOP; ++t) {
    const int rOff = (t & 1) * (17 * 256);

    // ---- consumer: acquire producer's row-15 h of step t-1 ----
    bf16x8 gfrag[4];
    if (half) {
      if (t >= 1 && t <= 47) {
        while (__hip_atomic_load(flag_b, __ATOMIC_ACQUIRE, __HIP_MEMORY_SCOPE_AGENT) < t)
          __builtin_amdgcn_s_sleep(2);
        const unsigned short* gp = ghost_b + (t - 1) * 128 + lg * 8;
#pragma unroll
        for (int kf = 0; kf < 4; ++kf)
          gfrag[kf] = *(const bf16x8*)(gp + kf * 32);
      } else {
#pragma unroll
        for (int kf = 0; kf < 4; ++kf) gfrag[kf] = (bf16x8){0, 0, 0, 0, 0, 0, 0, 0};
      }
    }

    f32x4 acc[4];
#pragma unroll
    for (int g = 0; g < 4; ++g) acc[g] = (f32x4){0.f, 0.f, 0.f, 0.f};

    // ---- fused input GEMM: z += W_is @ x(:, j, t-j) ----
    const int cLane = t - j0 - lm;
    const bool xv = ((unsigned)cLane < 32u);
    if (t >= j0) {  // wave-uniform: some lane in band
#pragma unroll
      for (int kf = 0; kf < 4; ++kf) {
        bf16x8 v = (bf16x8){0, 0, 0, 0, 0, 0, 0, 0};
        if (xv) {
          int row = lm * 32 + cLane;
          int addr = row * 256 + (((kf * 4 + lg) ^ (row & 15)) << 4);
          v = *(const bf16x8*)(xlsB + addr);
        }
#pragma unroll
        for (int g = 0; g < 4; ++g)
          acc[g] = __builtin_amdgcn_mfma_f32_16x16x32_bf16(Ais[g][kf], v, acc[g], 0, 0, 0);
      }
    }

    // ---- recurrent GEMM: W1@h first (kf 4..7), then W0@h_up (kf 0..3, ghost) ----
#pragma unroll
    for (int kf = 4; kf < 8; ++kf) {
      int chunk = (kf & 3) * 4 + lg;
      int addr = rOff + lm * 256 + ((chunk ^ (lm & 15)) << 4);
      bf16x8 v = *(const bf16x8*)((const char*)hTd + addr);
#pragma unroll
      for (int g = 0; g < 4; ++g)
        acc[g] = __builtin_amdgcn_mfma_f32_16x16x32_bf16(Ass[g][kf], v, acc[g], 0, 0, 0);
    }
#pragma unroll
    for (int kf = 0; kf < 4; ++kf) {
      int rr = (lm == 0) ? 16 : lm - 1;
      int chunk = kf * 4 + lg;
      int addr = rOff + rr * 256 + ((chunk ^ (rr & 15)) << 4);
      bf16x8 v = *(const bf16x8*)((const char*)hTd + addr);
      if (half && lm == 0) v = gfrag[kf];
#pragma unroll
      for (int g = 0; g < 4; ++g)
        acc[g] = __builtin_amdgcn_mfma_f32_16x16x32_bf16(Ass[g][kf], v, acc[g], 0, 0, 0);
    }

    // ---- lane-local LSTM cell ----
    unsigned short hb[4];
    float outv[4];
#pragma unroll
    for (int r = 0; r < 4; ++r) {
      float zo = acc[0][r] + bs[0][r];
      float zf = acc[1][r] + bs[1][r];
      float zi = acc[2][r] + bs[2][r];
      float zg = acc[3][r] + bs[3][r];
      float og = __fdividef(1.f, 1.f + __expf(-zo));
      float fg = __fdividef(1.f, 1.f + __expf(-zf));
      float ig = __fdividef(1.f, 1.f + __expf(-zi));
      float gg = 1.f - __fdividef(2.f, __expf(2.f * zg) + 1.f);
      float cn = fg * cst[r] + ig * gg;
      cst[r] = cn;
      float th = 1.f - __fdividef(2.f, __expf(2.f * cn) + 1.f);
      float hn = og * th;
      hb[r] = f2bf(hn);
      outv[r] = hn;
    }
    if (xv) {
      float* op = out + ((b * C_ + chW + lg * 4) * H_ + j0 + lm) * W_ + cLane;
#pragma unroll
      for (int r = 0; r < 4; ++r) op[r * (H_ * W_)] = outv[r];
    }
    // h -> other buffer
    *(us4*)((char*)hTd + (rOff ^ (17 * 256)) + wAddr) = *(us4*)hb;
    // producer: publish row-15 h
    if (!half && lm == 15)
      *(us4*)(ghost_b + t * 128 + chW + lg * 4) = *(us4*)hb;

    __syncthreads();
    if (!half && tid == 0)
      __hip_atomic_store(flag_b, t + 1, __ATOMIC_RELEASE, __HIP_MEMORY_SCOPE_AGENT);
  }
}

// ---------------------------------------------------------------------------
extern "C" void kernel_launch(void* const* d_in, const int* in_sizes, int n_in,
                              void* d_out, int out_size, void* d_ws, size_t ws_size,
                              hipStream_t stream) {
  const float* x    = (const float*)d_in[0];
  const float* W_is = (const float*)d_in[1];
  const float* b_is = (const float*)d_in[2];
  const float* W_ss = (const float*)d_in[3];
  const float* b_ss = (const float*)d_in[4];
  float* out = (float*)d_out;

  int* flags = (int*)d_ws;                                      // 32 ints
  unsigned short* ghost = (unsigned short*)((char*)d_ws + 1024); // 32*64*128 bf16 = 512KB

  (void)hipFuncSetAttribute((const void*)scan_kernel,
                            hipFuncAttributeMaxDynamicSharedMemorySize, LDS_BYTES);
  (void)hipMemsetAsync(d_ws, 0, 128, stream);  // reset flags each call
  scan_kernel<<<dim3(2 * B_), dim3(512), LDS_BYTES, stream>>>(
      x, W_is, b_is, W_ss, b_ss, out, flags, ghost);
}

// Round 4
// 336.144 us; speedup vs baseline: 1.2178x; 1.2178x over previous
//
#include <hip/hip_runtime.h>

#define B_ 32
#define C_ 128
#define H_ 32
#define W_ 32
#define WN 63
#define O_ 512  // 4*C

typedef __attribute__((ext_vector_type(8))) short bf16x8;
typedef __attribute__((ext_vector_type(4))) float f32x4;
typedef __attribute__((ext_vector_type(4))) unsigned short us4;

__device__ __forceinline__ unsigned short f2bf(float f) {
  union { float f; unsigned u; } v; v.f = f;
  unsigned r = v.u + 0x7FFFu + ((v.u >> 16) & 1u);
  return (unsigned short)(r >> 16);
}
__device__ __forceinline__ float bf2f(unsigned short h) {
  union { unsigned u; float f; } v; v.u = ((unsigned)h) << 16;
  return v.f;
}

// Diagonal-packed i_s layout: for step t, rows j in [jmin(t), jmax(t)] are
// stored contiguously: addr = (b*1024 + diag_off(t) + (j - jmin))*512 + o.
// diag_off(t) = prefix sum of band sizes; total 1024 rows per batch = 32 MiB bf16.
__device__ __forceinline__ int diag_off(int t) {
  return (t <= 31) ? (t * (t + 1) / 2) : (1024 - (63 - t) * (64 - t) / 2);
}

// ---------------------------------------------------------------------------
// Kernel 1: i_s (x-part, no bias) = W_is @ x per (b,j): 512x32, K=128.
// Stores bf16 into the diagonal-packed layout above.
// ---------------------------------------------------------------------------
__global__ __launch_bounds__(512, 2)
void is_kernel(const float* __restrict__ x, const float* __restrict__ W_is,
               unsigned short* __restrict__ is_ws) {
  const int bj = blockIdx.x;
  const int b = bj >> 5, j = bj & 31;
  const int tid = threadIdx.x;
  const int w = tid >> 6, l = tid & 63;
  const int lg = l >> 4, lm = l & 15;

  // xT: rows c (32), cols ch (128) bf16, 16B-chunk swizzled by (c&15)
  __shared__ __align__(16) unsigned short xT[32 * 128];

  {
    const int ch = tid & 127;
    const int cb = tid >> 7;  // 0..3 (block of 8 c's)
    const float* src = x + ((b * C_ + ch) * H_ + j) * W_ + cb * 8;
    f32x4 v0 = *(const f32x4*)(src);
    f32x4 v1 = *(const f32x4*)(src + 4);
    const int byteCol = ch * 2;
#pragma unroll
    for (int i = 0; i < 8; ++i) {
      int c = cb * 8 + i;
      float fv = (i < 4) ? v0[i & 3] : v1[i & 3];
      int addr = c * 256 + (((byteCol >> 4) ^ (c & 15)) << 4) + (byteCol & 15);
      *(unsigned short*)((char*)xT + addr) = f2bf(fv);
    }
  }
  __syncthreads();

  f32x4 acc[4][2];
#pragma unroll
  for (int g = 0; g < 4; ++g)
#pragma unroll
    for (int n = 0; n < 2; ++n) acc[g][n] = (f32x4){0.f, 0.f, 0.f, 0.f};

#pragma unroll
  for (int kf = 0; kf < 4; ++kf) {
    bf16x8 bfv[2];
#pragma unroll
    for (int n = 0; n < 2; ++n) {
      int c = n * 16 + lm;
      int chunk = kf * 4 + lg;
      int addr = c * 256 + ((chunk ^ (c & 15)) << 4);
      bfv[n] = *(const bf16x8*)((const char*)xT + addr);
    }
#pragma unroll
    for (int g = 0; g < 4; ++g) {
      const int o = g * 128 + 16 * w + lm;
      const float* wp = W_is + o * C_ + kf * 32 + lg * 8;
      f32x4 wa = *(const f32x4*)(wp);
      f32x4 wb = *(const f32x4*)(wp + 4);
      bf16x8 af;
      af[0] = (short)f2bf(wa[0]); af[1] = (short)f2bf(wa[1]);
      af[2] = (short)f2bf(wa[2]); af[3] = (short)f2bf(wa[3]);
      af[4] = (short)f2bf(wb[0]); af[5] = (short)f2bf(wb[1]);
      af[6] = (short)f2bf(wb[2]); af[7] = (short)f2bf(wb[3]);
#pragma unroll
      for (int n = 0; n < 2; ++n)
        acc[g][n] = __builtin_amdgcn_mfma_f32_16x16x32_bf16(af, bfv[n], acc[g][n], 0, 0, 0);
    }
  }

#pragma unroll
  for (int g = 0; g < 4; ++g)
#pragma unroll
    for (int n = 0; n < 2; ++n) {
      int c = n * 16 + lm;
      int o = g * 128 + 16 * w + lg * 4;
      int t = j + c;
      int jmin = (t > 31) ? (t - 31) : 0;
      us4 st;
#pragma unroll
      for (int r = 0; r < 4; ++r) st[r] = f2bf(acc[g][n][r]);
      *(us4*)(is_ws + (b * 1024 + diag_off(t) + (j - jmin)) * O_ + o) = st;
    }
}

// ---------------------------------------------------------------------------
// Kernel 2: diagonal scan. 32 blocks (one per batch), 512 threads (8 waves).
// Wave w owns channels [16w,16w+16); M-tiles {w,w+8,w+16,w+24} = gates
// o,f,i,g of those channels -> elementwise is lane-local in the accumulators.
// hT double-buffered -> ONE barrier per step. i_s prefetched one step ahead
// (contiguous 32KB slab per (b,t)).
// ---------------------------------------------------------------------------
__global__ __launch_bounds__(512, 2)
void scan_kernel(const float* __restrict__ Wss, const float* __restrict__ b_is,
                 const float* __restrict__ b_ss,
                 const unsigned short* __restrict__ is_ws,
                 float* __restrict__ out) {
  const int b = blockIdx.x;
  const int tid = threadIdx.x;
  const int w = tid >> 6, l = tid & 63;
  const int lg = l >> 4, lm = l & 15;
  const int chW = 16 * w;

  // hT[2][33][128] bf16: row 32 of each buffer = permanent zero row (h_up at
  // j==0). 16B-chunk swizzle by (row&15).
  __shared__ __align__(16) unsigned short hT[2 * 33 * 128];
  for (int i = tid; i < 2 * 33 * 128; i += 512) hT[i] = 0;

  // Recurrent weights [W0|W1] in registers: A[g][kf]; kf<4 -> W0 (h_up)
  bf16x8 A[4][8];
#pragma unroll
  for (int g = 0; g < 4; ++g) {
    const int o = g * 128 + chW + lm;
#pragma unroll
    for (int kf = 0; kf < 4; ++kf) {
      const int ch = kf * 32 + lg * 8;
      const float* wp = Wss + (o * C_ + ch) * 2;  // interleaved (W0,W1)
      f32x4 q0 = *(const f32x4*)(wp + 0);
      f32x4 q1 = *(const f32x4*)(wp + 4);
      f32x4 q2 = *(const f32x4*)(wp + 8);
      f32x4 q3 = *(const f32x4*)(wp + 12);
      bf16x8 a0, a1;
      a0[0] = (short)f2bf(q0[0]); a1[0] = (short)f2bf(q0[1]);
      a0[1] = (short)f2bf(q0[2]); a1[1] = (short)f2bf(q0[3]);
      a0[2] = (short)f2bf(q1[0]); a1[2] = (short)f2bf(q1[1]);
      a0[3] = (short)f2bf(q1[2]); a1[3] = (short)f2bf(q1[3]);
      a0[4] = (short)f2bf(q2[0]); a1[4] = (short)f2bf(q2[1]);
      a0[5] = (short)f2bf(q2[2]); a1[5] = (short)f2bf(q2[3]);
      a0[6] = (short)f2bf(q3[0]); a1[6] = (short)f2bf(q3[1]);
      a0[7] = (short)f2bf(q3[2]); a1[7] = (short)f2bf(q3[3]);
      A[g][kf] = a0;
      A[g][kf + 4] = a1;
    }
  }

  float bs[4][4];
#pragma unroll
  for (int g = 0; g < 4; ++g)
#pragma unroll
    for (int r = 0; r < 4; ++r) {
      int o = g * 128 + chW + lg * 4 + r;
      bs[g][r] = b_is[o] + b_ss[o];
    }

  float cst[2][4] = {{0.f, 0.f, 0.f, 0.f}, {0.f, 0.f, 0.f, 0.f}};

  // ---- i_s prefetch helper (diag-packed, contiguous per (b,t)) ----
  us4 isv[4][2], isvN[4][2];
  auto load_is = [&](int t, us4 (&iv)[4][2], int nLo) {
    const int jmin = (t > 31) ? (t - 31) : 0;
    const unsigned short* base = is_ws + (b * 1024 + diag_off(t) - jmin) * O_;
#pragma unroll
    for (int n = 0; n < 2; ++n) {
      const int j = n * 16 + lm;
      const bool valid = (n >= nLo) && ((unsigned)(t - j) < 32u);
      const unsigned short* p = base + j * O_ + chW + lg * 4;
#pragma unroll
      for (int g = 0; g < 4; ++g) {
        if (valid) iv[g][n] = *(const us4*)(p + g * 128);
        else       iv[g][n] = (us4){0, 0, 0, 0};
      }
    }
  };

  load_is(0, isv, 0);
  __syncthreads();

  for (int t = 0; t < WN; ++t) {
    const int nLo = (t < 47) ? 0 : 1;  // rows j<16 dead once t-31 > 15
    const int rOff = (t & 1) * (33 * 256);
    const int wOff = rOff ^ (33 * 256);

    // ---- GEMM: z = [W0|W1] @ [h_up; h] from read buffer ----
    f32x4 acc[4][2];
#pragma unroll
    for (int g = 0; g < 4; ++g)
#pragma unroll
      for (int n = 0; n < 2; ++n) acc[g][n] = (f32x4){0.f, 0.f, 0.f, 0.f};

#pragma unroll
    for (int n = 0; n < 2; ++n) {
      if (n >= nLo) {
        const int j = n * 16 + lm;
        const int rU = (j == 0) ? 32 : j - 1;
#pragma unroll
        for (int kf = 0; kf < 8; ++kf) {
          const int rr = (kf < 4) ? rU : j;
          const int chunk = (kf & 3) * 4 + lg;
          const int addr = rOff + rr * 256 + ((chunk ^ (rr & 15)) << 4);
          bf16x8 bfv = *(const bf16x8*)((const char*)hT + addr);
#pragma unroll
          for (int g = 0; g < 4; ++g)
            acc[g][n] = __builtin_amdgcn_mfma_f32_16x16x32_bf16(A[g][kf], bfv, acc[g][n], 0, 0, 0);
        }
      }
    }

    // ---- prefetch i_s for t+1 (rides across the barrier) ----
    if (t + 1 < WN) load_is(t + 1, isvN, (t + 1 < 47) ? 0 : 1);

    // ---- lane-local LSTM cell + writes ----
#pragma unroll
    for (int n = 0; n < 2; ++n) {
      if (n >= nLo) {
        const int j = n * 16 + lm;
        const int c = t - j;
        const bool inband = ((unsigned)c < 32u);
        unsigned short hb[4];
#pragma unroll
        for (int r = 0; r < 4; ++r) {
          float zo = acc[0][n][r] + bf2f(isv[0][n][r]) + bs[0][r];
          float zf = acc[1][n][r] + bf2f(isv[1][n][r]) + bs[1][r];
          float zi = acc[2][n][r] + bf2f(isv[2][n][r]) + bs[2][r];
          float zg = acc[3][n][r] + bf2f(isv[3][n][r]) + bs[3][r];
          float og = __fdividef(1.f, 1.f + __expf(-zo));
          float fg = __fdividef(1.f, 1.f + __expf(-zf));
          float ig = __fdividef(1.f, 1.f + __expf(-zi));
          float gg = 1.f - __fdividef(2.f, __expf(2.f * zg) + 1.f);
          float cn = fg * cst[n][r] + ig * gg;
          cst[n][r] = cn;
          float th = 1.f - __fdividef(2.f, __expf(2.f * cn) + 1.f);
          float hn = og * th;
          hb[r] = f2bf(hn);
          if (inband)
            out[((b * C_ + (chW + lg * 4 + r)) * H_ + j) * W_ + c] = hn;
        }
        // write h (bf16) into the WRITE buffer, swizzled
        const int byteCol = chW * 2 + lg * 8;
        const int chunk = byteCol >> 4;
        const int addr = wOff + j * 256 + ((chunk ^ (j & 15)) << 4) + (byteCol & 15);
        *(us4*)((char*)hT + addr) = *(us4*)hb;
      }
    }

    __syncthreads();  // write buffer complete -> becomes next read buffer
#pragma unroll
    for (int g = 0; g < 4; ++g)
#pragma unroll
      for (int n = 0; n < 2; ++n) isv[g][n] = isvN[g][n];
  }
}

// ---------------------------------------------------------------------------
extern "C" void kernel_launch(void* const* d_in, const int* in_sizes, int n_in,
                              void* d_out, int out_size, void* d_ws, size_t ws_size,
                              hipStream_t stream) {
  const float* x    = (const float*)d_in[0];
  const float* W_is = (const float*)d_in[1];
  const float* b_is = (const float*)d_in[2];
  const float* W_ss = (const float*)d_in[3];
  const float* b_ss = (const float*)d_in[4];
  float* out = (float*)d_out;
  unsigned short* is_ws = (unsigned short*)d_ws;  // 32 MiB diag-packed bf16

  is_kernel<<<dim3(B_ * H_), dim3(512), 0, stream>>>(x, W_is, is_ws);
  scan_kernel<<<dim3(B_), dim3(512), 0, stream>>>(W_ss, b_is, b_ss, is_ws, out);
}

// Round 5
// 254.321 us; speedup vs baseline: 1.6096x; 1.3217x over previous
//
#include <hip/hip_runtime.h>

#define B_ 32
#define C_ 128
#define H_ 32
#define W_ 32
#define WN 63
#define O_ 512              // 4*C
#define HTB (33 * 256)      // bytes per hT buffer
#define BIAS_ROW 32768      // shared bias row index in is_ws

typedef __attribute__((ext_vector_type(8))) short bf16x8;
typedef __attribute__((ext_vector_type(4))) float f32x4;
typedef __attribute__((ext_vector_type(4))) unsigned short us4;

#define L2E 1.442695041f
#define L2E2 2.885390082f

__device__ __forceinline__ unsigned short f2bf(float f) {
  union { float f; unsigned u; } v; v.f = f;
  unsigned r = v.u + 0x7FFFu + ((v.u >> 16) & 1u);
  return (unsigned short)(r >> 16);
}
__device__ __forceinline__ float bf2f(unsigned short h) {
  union { unsigned u; float f; } v; v.u = ((unsigned)h) << 16;
  return v.f;
}

// Diagonal-packed i_s: step t's rows j in [jmin, jmax] stored contiguously at
// (b*1024 + diag_off(t) + (j - jmin)); 1024 rows per batch; values hold
// (i_s + b_is + b_ss) * (gate==3 ? 2*log2e : log2e) in bf16.
__device__ __forceinline__ int diag_off(int t) {
  return (t <= 31) ? (t * (t + 1) / 2) : (1024 - (63 - t) * (64 - t) / 2);
}

// ---------------------------------------------------------------------------
// Kernel 1: per (b, jq) block computes i_s for 4 j-rows (512x128 GEMM, K=128).
// ---------------------------------------------------------------------------
__global__ __launch_bounds__(512, 2)
void is_kernel(const float* __restrict__ x, const float* __restrict__ W_is,
               const float* __restrict__ b_is, const float* __restrict__ b_ss,
               unsigned short* __restrict__ is_ws) {
  const int bid = blockIdx.x;
  const int b = bid >> 3, jq = bid & 7;
  const int tid = threadIdx.x;
  const int w = tid >> 6, l = tid & 63;
  const int lg = l >> 4, lm = l & 15;

  // shared bias row (block 0 only): (b_is+b_ss)*SC
  if (bid == 0) {
    float v = (b_is[tid] + b_ss[tid]) * ((tid >> 7) == 3 ? L2E2 : L2E);
    is_ws[(size_t)BIAS_ROW * O_ + tid] = f2bf(v);
  }

  // xT: rows rr = jl*32 + c (128 rows) x 128 ch bf16, 16B-chunk swizzle by rr&15
  __shared__ __align__(16) unsigned short xT[128 * 128];
#pragma unroll
  for (int it = 0; it < 32; ++it) {
    int idx = it * 512 + tid;
    int c = idx & 31, jl = (idx >> 5) & 3, ch = idx >> 7;
    float v = x[((b * C_ + ch) * H_ + jq * 4 + jl) * W_ + c];
    int rr = jl * 32 + c;
    int byteCol = ch * 2;
    int addr = rr * 256 + (((byteCol >> 4) ^ (rr & 15)) << 4) + (byteCol & 15);
    *(unsigned short*)((char*)xT + addr) = f2bf(v);
  }
  __syncthreads();

  f32x4 acc[4][8];
#pragma unroll
  for (int g = 0; g < 4; ++g)
#pragma unroll
    for (int nt = 0; nt < 8; ++nt) acc[g][nt] = (f32x4){0.f, 0.f, 0.f, 0.f};

#pragma unroll
  for (int kf = 0; kf < 4; ++kf) {
    bf16x8 bfv[8];
#pragma unroll
    for (int nt = 0; nt < 8; ++nt) {
      int rr = (nt >> 1) * 32 + (nt & 1) * 16 + lm;
      int chunk = kf * 4 + lg;
      int addr = rr * 256 + ((chunk ^ (rr & 15)) << 4);
      bfv[nt] = *(const bf16x8*)((const char*)xT + addr);
    }
#pragma unroll
    for (int g = 0; g < 4; ++g) {
      const int o = g * 128 + 16 * w + lm;
      const float* wp = W_is + o * C_ + kf * 32 + lg * 8;
      f32x4 wa = *(const f32x4*)(wp);
      f32x4 wb = *(const f32x4*)(wp + 4);
      bf16x8 af;
      af[0] = (short)f2bf(wa[0]); af[1] = (short)f2bf(wa[1]);
      af[2] = (short)f2bf(wa[2]); af[3] = (short)f2bf(wa[3]);
      af[4] = (short)f2bf(wb[0]); af[5] = (short)f2bf(wb[1]);
      af[6] = (short)f2bf(wb[2]); af[7] = (short)f2bf(wb[3]);
#pragma unroll
      for (int nt = 0; nt < 8; ++nt)
        acc[g][nt] = __builtin_amdgcn_mfma_f32_16x16x32_bf16(af, bfv[nt], acc[g][nt], 0, 0, 0);
    }
  }

#pragma unroll
  for (int g = 0; g < 4; ++g) {
    const float sc = (g == 3) ? L2E2 : L2E;
    const int ob = g * 128 + 16 * w + lg * 4;
#pragma unroll
    for (int nt = 0; nt < 8; ++nt) {
      int jl = nt >> 1;
      int c = (nt & 1) * 16 + lm;
      int j = jq * 4 + jl;
      int t = j + c;
      int jmin = (t > 31) ? (t - 31) : 0;
      us4 st;
#pragma unroll
      for (int r = 0; r < 4; ++r)
        st[r] = f2bf((acc[g][nt][r] + b_is[ob + r] + b_ss[ob + r]) * sc);
      *(us4*)(is_ws + (size_t)(b * 1024 + diag_off(t) + (j - jmin)) * O_ + ob) = st;
    }
  }
}

// ---------------------------------------------------------------------------
// Kernel 2: diagonal scan. 32 blocks (one per batch), 512 threads (8 waves).
// Wave w: channels [16w,16w+16), M-tiles {w,w+8,w+16,w+24} = gates o,f,i,g.
// acc initialized from prescaled (i_s+bias) -> no post-GEMM adds. Cell uses
// exp2/rcp (weights prescaled by log2e). 2x-unrolled step loop, dbuf hT,
// one barrier per step, alternating isv register buffers (no copies).
// ---------------------------------------------------------------------------
__global__ __launch_bounds__(512, 2)
void scan_kernel(const float* __restrict__ Wss,
                 const unsigned short* __restrict__ is_ws,
                 float* __restrict__ out) {
  const int b = blockIdx.x;
  const int tid = threadIdx.x;
  const int w = tid >> 6, l = tid & 63;
  const int lg = l >> 4, lm = l & 15;
  const int chW = 16 * w;

  __shared__ __align__(16) unsigned short hT[2 * 33 * 128];
  for (int i = tid; i < 2 * 33 * 128; i += 512) hT[i] = 0;

  // Recurrent weights [W0|W1], prescaled by SC[g]: A[g][kf], kf<4 -> W0 (h_up)
  bf16x8 A[4][8];
#pragma unroll
  for (int g = 0; g < 4; ++g) {
    const float sc = (g == 3) ? L2E2 : L2E;
    const int o = g * 128 + chW + lm;
#pragma unroll
    for (int kf = 0; kf < 4; ++kf) {
      const int ch = kf * 32 + lg * 8;
      const float* wp = Wss + (o * C_ + ch) * 2;  // interleaved (W0,W1)
      f32x4 q0 = *(const f32x4*)(wp + 0);
      f32x4 q1 = *(const f32x4*)(wp + 4);
      f32x4 q2 = *(const f32x4*)(wp + 8);
      f32x4 q3 = *(const f32x4*)(wp + 12);
      bf16x8 a0, a1;
      a0[0] = (short)f2bf(q0[0] * sc); a1[0] = (short)f2bf(q0[1] * sc);
      a0[1] = (short)f2bf(q0[2] * sc); a1[1] = (short)f2bf(q0[3] * sc);
      a0[2] = (short)f2bf(q1[0] * sc); a1[2] = (short)f2bf(q1[1] * sc);
      a0[3] = (short)f2bf(q1[2] * sc); a1[3] = (short)f2bf(q1[3] * sc);
      a0[4] = (short)f2bf(q2[0] * sc); a1[4] = (short)f2bf(q2[1] * sc);
      a0[5] = (short)f2bf(q2[2] * sc); a1[5] = (short)f2bf(q2[3] * sc);
      a0[6] = (short)f2bf(q3[0] * sc); a1[6] = (short)f2bf(q3[1] * sc);
      a0[7] = (short)f2bf(q3[2] * sc); a1[7] = (short)f2bf(q3[3] * sc);
      A[g][kf] = a0;
      A[g][kf + 4] = a1;
    }
  }

  float cst[2][4] = {{0.f, 0.f, 0.f, 0.f}, {0.f, 0.f, 0.f, 0.f}};
  us4 isvA[4][2], isvB[4][2];

  auto load_is = [&](int t, us4 (&iv)[4][2]) {
    const int jmin = (t > 31) ? (t - 31) : 0;
    const int dOff = b * 1024 + diag_off(t) - jmin;
#pragma unroll
    for (int n = 0; n < 2; ++n) {
      const int j = n * 16 + lm;
      const bool valid = ((unsigned)(t - j) < 32u);
      const int row = valid ? (dOff + j) : BIAS_ROW;
      const unsigned short* p = is_ws + (size_t)row * O_ + chW + lg * 4;
#pragma unroll
      for (int g = 0; g < 4; ++g) iv[g][n] = *(const us4*)(p + g * 128);
    }
  };

  auto step_body = [&](int t, int rOff, int wOff, us4 (&isv)[4][2],
                       us4 (&isvN)[4][2], bool pf) {
    const int nLo = (t < 47) ? 0 : 1;  // rows j<16 dead once t-31 > 15

    f32x4 acc[4][2];
#pragma unroll
    for (int n = 0; n < 2; ++n) {
      if (n >= nLo) {
#pragma unroll
        for (int g = 0; g < 4; ++g)
#pragma unroll
          for (int r = 0; r < 4; ++r) acc[g][n][r] = bf2f(isv[g][n][r]);
        const int j = n * 16 + lm;
        const int rU = (j == 0) ? 32 : j - 1;
#pragma unroll
        for (int kf = 0; kf < 8; ++kf) {
          const int rr = (kf < 4) ? rU : j;
          const int chunk = (kf & 3) * 4 + lg;
          const int addr = rOff + rr * 256 + ((chunk ^ (rr & 15)) << 4);
          bf16x8 bfv = *(const bf16x8*)((const char*)hT + addr);
#pragma unroll
          for (int g = 0; g < 4; ++g)
            acc[g][n] = __builtin_amdgcn_mfma_f32_16x16x32_bf16(A[g][kf], bfv, acc[g][n], 0, 0, 0);
        }
      }
    }

    if (pf) load_is(t + 1, isvN);

#pragma unroll
    for (int n = 0; n < 2; ++n) {
      if (n >= nLo) {
        const int j = n * 16 + lm;
        const int c = t - j;
        const bool inband = ((unsigned)c < 32u);
        unsigned short hb[4];
#pragma unroll
        for (int r = 0; r < 4; ++r) {
          // acc already holds prescaled z (incl. i_s + biases)
          float so = __builtin_amdgcn_rcpf(1.f + exp2f(-acc[0][n][r]));
          float sf = __builtin_amdgcn_rcpf(1.f + exp2f(-acc[1][n][r]));
          float si = __builtin_amdgcn_rcpf(1.f + exp2f(-acc[2][n][r]));
          float gg = 2.f * __builtin_amdgcn_rcpf(1.f + exp2f(-acc[3][n][r])) - 1.f;
          float cn = sf * cst[n][r] + si * gg;
          cst[n][r] = cn;
          float th = 2.f * __builtin_amdgcn_rcpf(1.f + exp2f(cn * -L2E2)) - 1.f;
          float hn = so * th;
          hb[r] = f2bf(hn);
          if (inband)
            out[((b * C_ + (chW + lg * 4 + r)) * H_ + j) * W_ + c] = hn;
        }
        const int byteCol = chW * 2 + lg * 8;
        const int chunk = byteCol >> 4;
        const int addr = wOff + j * 256 + ((chunk ^ (j & 15)) << 4) + (byteCol & 15);
        *(us4*)((char*)hT + addr) = *(us4*)hb;
      }
    }

    __syncthreads();
  };

  load_is(0, isvA);
  __syncthreads();

  for (int t = 0; t < WN - 1; t += 2) {
    step_body(t, 0, HTB, isvA, isvB, true);
    step_body(t + 1, HTB, 0, isvB, isvA, t + 2 < WN);
  }
  step_body(WN - 1, 0, HTB, isvA, isvB, false);
}

// ---------------------------------------------------------------------------
extern "C" void kernel_launch(void* const* d_in, const int* in_sizes, int n_in,
                              void* d_out, int out_size, void* d_ws, size_t ws_size,
                              hipStream_t stream) {
  const float* x    = (const float*)d_in[0];
  const float* W_is = (const float*)d_in[1];
  const float* b_is = (const float*)d_in[2];
  const float* W_ss = (const float*)d_in[3];
  const float* b_ss = (const float*)d_in[4];
  float* out = (float*)d_out;
  unsigned short* is_ws = (unsigned short*)d_ws;  // 32 MiB + bias row

  is_kernel<<<dim3(B_ * 8), dim3(512), 0, stream>>>(x, W_is, b_is, b_ss, is_ws);
  scan_kernel<<<dim3(B_), dim3(512), 0, stream>>>(W_ss, is_ws, out);
}